// Round 4
// baseline (272.258 us; speedup 1.0000x reference)
//
#include <hip/hip_runtime.h>
#include <math.h>

// SPDNet collapse: both ReEig clamps are inactive (lambda_min >= 1e-3 > 1e-4 by
// construction), so:  out = vec(logm(V^T x V)) @ w_lin^T + b_lin,  V = w1@w2.
// One thread per matrix; 11x11 Jacobi fully unrolled in registers.
//
// R11 (R10 post-mortem: R7->R10 shows constant ~9.4 cyc/instr at 1 wave/SIMD;
// R8/R9's 128-reg builds ran 2 waves/SIMD -> HW pool ~256 regs/SIMD, so 2 waves
// needs <=128 VGPR: impossible with M66+U132 state. Occupancy closed. I$ theory
// refuted (R7 32KB vs R10 29KB sweep body straddles L1I, speedup stayed linear).
// Remaining stall = dep latency under the 5 per-round transcendental cs chains):
//  - software-pipeline U by ONE ROUND: round R applies round R-1's U-updates
//    (U depends only on (c,s), never on M) while round R's cs chains
//    (sqrt->rcp->rsq, ~50cyc) are in flight. 120 independent pk instrs overlay
//    the chain latency. Rotation order preserved (lagged) -> bit-identical.
//    First-ever round applies identity (c=1,s=0) on round-10 pairs (exact on
//    +0-initialized U); drain after the sweep loop applies the final round's U.
//  - carried state: cp[5], sp[5] (+10 VGPR, ~230-240 total; watch scratch).
//  - keep: waves_per_eu(1,1) (documents the 1-wave HW reality), NSWEEP 5,
//    round-phase split, copysign chain, packed U/epilogue, prep kernel.

#define NSWEEP 5

// d_ws float layout: [0..143] V (12x12, col 11 zero) | [160..211] b_lin |
//                    [256..256+52*68) Ws_sym rows padded to 68
#define WS_V 0
#define WS_B 160
#define WS_W 256

typedef float v2f __attribute__((ext_vector_type(2)));

__device__ __forceinline__ v2f fma2(v2f a, v2f b, v2f c) {
  return __builtin_elementwise_fma(a, b, c);
}
__device__ __forceinline__ v2f sp2(float x) {
  v2f r; r.x = x; r.y = x; return r;
}

__device__ __forceinline__ constexpr int UT(int i, int j) { // i<=j, n=11 upper tri
  return i * 11 - (i * (i - 1)) / 2 + (j - i);
}

template <int P, int Q>
__device__ __forceinline__ void csCompute(const float (&M)[66], float& c, float& s,
                                          float& t) {
  const float app = M[UT(P, P)], aqq = M[UT(Q, Q)], apq = M[UT(P, Q)];
  const float d2 = aqq - app;
  const float a2 = apq + apq;
  const float r = __builtin_amdgcn_sqrtf(
      __builtin_fmaf(d2, d2, __builtin_fmaf(a2, a2, 1e-60f)));
  const float den = d2 + __builtin_copysignf(r, d2);
  t = a2 * __builtin_amdgcn_rcpf(den);
  c = __builtin_amdgcn_rsqf(__builtin_fmaf(t, t, 1.0f));
  s = t * c;
}

// U2: column-major packed, col j = U2[j*6 .. j*6+5], rows (2*r2, 2*r2+1);
// row 11 is padding (stays 0, never read back).
template <int P, int Q>
__device__ __forceinline__ void applyU(v2f (&U2)[66], float c, float s) {
  const v2f c2 = sp2(c), s2 = sp2(s);
#pragma unroll
  for (int r2 = 0; r2 < 6; ++r2) {
    const v2f up = U2[P * 6 + r2], uq = U2[Q * 6 + r2];
    U2[P * 6 + r2] = fma2(c2, up, -(s2 * uq));   // c*up - s*uq  (2 rows/op)
    U2[Q * 6 + r2] = fma2(s2, up, c2 * uq);      // s*up + c*uq
  }
}

// M: scalar upper-tri (66).
template <int P, int Q>
__device__ __forceinline__ void applyM(float (&M)[66], float c, float s, float t) {
  const float apq = M[UT(P, Q)];
#pragma unroll
  for (int k = 0; k < 11; ++k) {
    if (k == P || k == Q) continue;
    const int ikp = (k < P) ? UT(k, P) : UT(P, k);
    const int ikq = (k < Q) ? UT(k, Q) : UT(Q, k);
    const float akp = M[ikp], akq = M[ikq];
    M[ikp] = __builtin_fmaf(c, akp, -s * akq);
    M[ikq] = __builtin_fmaf(s, akp, c * akq);
  }
  M[UT(P, P)] = __builtin_fmaf(-t, apq, M[UT(P, P)]);
  M[UT(Q, Q)] = __builtin_fmaf(t, apq, M[UT(Q, Q)]);
  M[UT(P, Q)] = 0.0f;
}

// Round-robin pairs: round R, K=1..5 -> 5 disjoint pairs; 11 rounds = all 55.
template <int R, int K>
struct PairRR {
  static constexpr int A0 = (R + K) % 11;
  static constexpr int B0 = (R + 11 - K) % 11;
  static constexpr int P = A0 < B0 ? A0 : B0;
  static constexpr int Q = A0 < B0 ? B0 : A0;
};

// Round R: (1) compute this round's cs chains, (2) apply PREVIOUS round's
// U-updates (independent of M/cs -> overlays the transcendental latency),
// (3) apply this round's M-updates, (4) carry cs for the next round's U.
template <int R>
__device__ __forceinline__ void jround(float (&M)[66], v2f (&U2)[66],
                                       float (&cp)[5], float (&sp)[5]) {
  constexpr int RP = (R + 10) % 11;  // previous round (mod 11, wraps sweeps)
  float c1, s1, t1, c2, s2, t2, c3, s3, t3, c4, s4, t4, c5, s5, t5;
  csCompute<PairRR<R, 1>::P, PairRR<R, 1>::Q>(M, c1, s1, t1);
  csCompute<PairRR<R, 2>::P, PairRR<R, 2>::Q>(M, c2, s2, t2);
  csCompute<PairRR<R, 3>::P, PairRR<R, 3>::Q>(M, c3, s3, t3);
  csCompute<PairRR<R, 4>::P, PairRR<R, 4>::Q>(M, c4, s4, t4);
  csCompute<PairRR<R, 5>::P, PairRR<R, 5>::Q>(M, c5, s5, t5);
  applyU<PairRR<RP, 1>::P, PairRR<RP, 1>::Q>(U2, cp[0], sp[0]);
  applyU<PairRR<RP, 2>::P, PairRR<RP, 2>::Q>(U2, cp[1], sp[1]);
  applyU<PairRR<RP, 3>::P, PairRR<RP, 3>::Q>(U2, cp[2], sp[2]);
  applyU<PairRR<RP, 4>::P, PairRR<RP, 4>::Q>(U2, cp[3], sp[3]);
  applyU<PairRR<RP, 5>::P, PairRR<RP, 5>::Q>(U2, cp[4], sp[4]);
  applyM<PairRR<R, 1>::P, PairRR<R, 1>::Q>(M, c1, s1, t1);
  applyM<PairRR<R, 2>::P, PairRR<R, 2>::Q>(M, c2, s2, t2);
  applyM<PairRR<R, 3>::P, PairRR<R, 3>::Q>(M, c3, s3, t3);
  applyM<PairRR<R, 4>::P, PairRR<R, 4>::Q>(M, c4, s4, t4);
  applyM<PairRR<R, 5>::P, PairRR<R, 5>::Q>(M, c5, s5, t5);
  cp[0] = c1; sp[0] = s1;
  cp[1] = c2; sp[1] = s2;
  cp[2] = c3; sp[2] = s3;
  cp[3] = c4; sp[3] = s4;
  cp[4] = c5; sp[4] = s5;
}

template <int R>
struct RoundSeq {
  static __device__ __forceinline__ void run(float (&M)[66], v2f (&U2)[66],
                                             float (&cp)[5], float (&sp)[5]) {
    jround<R>(M, U2, cp, sp);
    if constexpr (R < 10) RoundSeq<R + 1>::run(M, U2, cp, sp);
  }
};

__global__ __launch_bounds__(256) void prep_kernel(
    const float* __restrict__ w1, const float* __restrict__ w2,
    const float* __restrict__ wlin, const float* __restrict__ blin,
    float* __restrict__ ws) {
  const int g = blockIdx.x * 256 + threadIdx.x;
  const int gs = gridDim.x * 256;
  for (int idx = g; idx < 144; idx += gs) {
    const int i = idx / 12, l = idx % 12;
    float acc = 0.f;
    if (l < 11) {
#pragma unroll
      for (int j = 0; j < 12; ++j) acc = __builtin_fmaf(w1[i * 12 + j], w2[j * 11 + l], acc);
    }
    ws[WS_V + idx] = acc;
  }
  for (int idx = g; idx < 52; idx += gs) ws[WS_B + idx] = blin[idx];
  for (int idx = g; idx < 52 * 68; idx += gs) {
    const int c = idx / 68, t = idx % 68;
    float v = 0.f;
    if (t < 66) {
      int i = 0, rem = t;
      while (rem >= 11 - i) { rem -= 11 - i; ++i; }
      const int j = i + rem;
      v = wlin[c * 121 + i * 11 + j];
      if (i != j) v += wlin[c * 121 + j * 11 + i];
    }
    ws[WS_W + idx] = v;
  }
}

__global__ __attribute__((amdgpu_flat_work_group_size(256, 256)))
__attribute__((amdgpu_waves_per_eu(1, 1)))
void manifold_kernel(const float* __restrict__ x, const float* __restrict__ ws,
                     float* __restrict__ out, int B) {
  __shared__ __align__(16) float sV[12 * 12];
  const int tid = threadIdx.x;
  if (tid < 36) {
    reinterpret_cast<float4*>(sV)[tid] =
        reinterpret_cast<const float4*>(ws + WS_V)[tid];
  }
  __syncthreads();

  const int b = blockIdx.x * 256 + tid;
  if (b >= B) return;

  // ---- Formation: M = V^T (X V), 4 X-rows per block. w packed along l
  // (v2f w2[4][6]; pad lane l=11 multiplies V col 11 == 0, stays 0).
  float M[66];
#pragma unroll
  for (int e = 0; e < 66; ++e) M[e] = 0.f;
  const float4* xb4 = reinterpret_cast<const float4*>(x + (size_t)b * 144);
#pragma unroll 1
  for (int ib = 0; ib < 3; ++ib) {
    float xr[4][12];
#pragma unroll
    for (int r = 0; r < 4; ++r) {
      const float4 a0 = xb4[(ib * 4 + r) * 3 + 0];
      const float4 a1 = xb4[(ib * 4 + r) * 3 + 1];
      const float4 a2 = xb4[(ib * 4 + r) * 3 + 2];
      xr[r][0] = a0.x; xr[r][1] = a0.y; xr[r][2] = a0.z; xr[r][3] = a0.w;
      xr[r][4] = a1.x; xr[r][5] = a1.y; xr[r][6] = a1.z; xr[r][7] = a1.w;
      xr[r][8] = a2.x; xr[r][9] = a2.y; xr[r][10] = a2.z; xr[r][11] = a2.w;
    }
    v2f w2[4][6];
#pragma unroll
    for (int r = 0; r < 4; ++r)
#pragma unroll
      for (int l2 = 0; l2 < 6; ++l2) { w2[r][l2].x = 0.f; w2[r][l2].y = 0.f; }
#pragma unroll
    for (int j = 0; j < 12; ++j) {
      v2f vj[6];
      {
        const float4 v0 = *reinterpret_cast<const float4*>(&sV[j * 12 + 0]);
        const float4 v1 = *reinterpret_cast<const float4*>(&sV[j * 12 + 4]);
        const float4 v2 = *reinterpret_cast<const float4*>(&sV[j * 12 + 8]);
        vj[0].x = v0.x; vj[0].y = v0.y; vj[1].x = v0.z; vj[1].y = v0.w;
        vj[2].x = v1.x; vj[2].y = v1.y; vj[3].x = v1.z; vj[3].y = v1.w;
        vj[4].x = v2.x; vj[4].y = v2.y; vj[5].x = v2.z; vj[5].y = v2.w;
      }
#pragma unroll
      for (int r = 0; r < 4; ++r) {
        const v2f xb = sp2(xr[r][j]);
#pragma unroll
        for (int l2 = 0; l2 < 6; ++l2) w2[r][l2] = fma2(xb, vj[l2], w2[r][l2]);
      }
    }
#pragma unroll
    for (int r = 0; r < 4; ++r) {
      const int i = ib * 4 + r;
      const float4 u0 = *reinterpret_cast<const float4*>(&sV[i * 12 + 0]);
      const float4 u1 = *reinterpret_cast<const float4*>(&sV[i * 12 + 4]);
      const float4 u2 = *reinterpret_cast<const float4*>(&sV[i * 12 + 8]);
      const float ui[11] = {u0.x, u0.y, u0.z, u0.w, u1.x, u1.y, u1.z, u1.w,
                            u2.x, u2.y, u2.z};
      float wv[11];  // free register aliases of w2 halves
#pragma unroll
      for (int l = 0; l < 11; ++l)
        wv[l] = (l & 1) ? w2[r][l >> 1].y : w2[r][l >> 1].x;
#pragma unroll
      for (int k = 0; k < 11; ++k)
#pragma unroll
        for (int l = k; l < 11; ++l)
          M[UT(k, l)] = __builtin_fmaf(ui[k], wv[l], M[UT(k, l)]);
    }
  }

  // ---- Jacobi eigendecomposition; U column-major packed in v2f,
  // U-updates software-pipelined one round behind the M/cs stream ----
  v2f U2[66];
#pragma unroll
  for (int e = 0; e < 66; ++e) { U2[e].x = 0.f; U2[e].y = 0.f; }
#pragma unroll
  for (int d = 0; d < 11; ++d) {
    if (d & 1) U2[d * 6 + (d >> 1)].y = 1.f;
    else       U2[d * 6 + (d >> 1)].x = 1.f;
  }
  float cp[5] = {1.f, 1.f, 1.f, 1.f, 1.f};   // identity rotations for the
  float sp[5] = {0.f, 0.f, 0.f, 0.f, 0.f};   // very first round's U-prev
#pragma unroll 1
  for (int sweep = 0; sweep < NSWEEP; ++sweep) {
    RoundSeq<0>::run(M, U2, cp, sp);
  }
  // drain: apply the final round's (round 10) U-updates
  applyU<PairRR<10, 1>::P, PairRR<10, 1>::Q>(U2, cp[0], sp[0]);
  applyU<PairRR<10, 2>::P, PairRR<10, 2>::Q>(U2, cp[1], sp[1]);
  applyU<PairRR<10, 3>::P, PairRR<10, 3>::Q>(U2, cp[2], sp[2]);
  applyU<PairRR<10, 4>::P, PairRR<10, 4>::Q>(U2, cp[3], sp[3]);
  applyU<PairRR<10, 5>::P, PairRR<10, 5>::Q>(U2, cp[4], sp[4]);

  // ---- eigen-log (clamp matches the reference's preceding ReEig) ----
  float lw[11];
#pragma unroll
  for (int k = 0; k < 11; ++k) lw[k] = __logf(fmaxf(M[UT(k, k)], 1e-4f));

  // ---- L = U diag(lw) U^T, written directly into packed v2f L2[33].
  // U[i][k] = (row i, col k) = half (i&1) of U2[k*6 + (i>>1)] -- free alias.
  v2f L2[33];
#pragma unroll
  for (int i = 0; i < 11; ++i) {
    float tk[11];
#pragma unroll
    for (int k = 0; k < 11; ++k) {
      const v2f u = U2[k * 6 + (i >> 1)];
      const float uik = (i & 1) ? u.y : u.x;
      tk[k] = lw[k] * uik;
    }
#pragma unroll
    for (int j = i; j < 11; ++j) {
      float acc = 0.f;
#pragma unroll
      for (int k = 0; k < 11; ++k) {
        const v2f u = U2[k * 6 + (j >> 1)];
        const float ujk = (j & 1) ? u.y : u.x;
        acc = __builtin_fmaf(tk[k], ujk, acc);
      }
      const int idx = UT(i, j);
      if (idx & 1) L2[idx >> 1].y = acc;
      else         L2[idx >> 1].x = acc;
    }
  }

  // ---- epilogue: packed pk_fma; weights wave-uniform (SGPR-pair source) ----
  const float* __restrict__ wsym = ws + WS_W;
  const float* __restrict__ bl = ws + WS_B;
  float* ob = out + (size_t)b * 52;
#pragma unroll 1
  for (int c4 = 0; c4 < 13; ++c4) {
    float ov[4];
#pragma unroll
    for (int cc = 0; cc < 4; ++cc) {
      const int c = c4 * 4 + cc;
      const v2f* __restrict__ wr2 = reinterpret_cast<const v2f*>(wsym + c * 68);
      v2f a0 = sp2(0.f), a1 = sp2(0.f), a2 = sp2(0.f);
#pragma unroll
      for (int t = 0; t < 30; t += 3) {
        a0 = fma2(wr2[t + 0], L2[t + 0], a0);
        a1 = fma2(wr2[t + 1], L2[t + 1], a1);
        a2 = fma2(wr2[t + 2], L2[t + 2], a2);
      }
      a0 = fma2(wr2[30], L2[30], a0);
      a1 = fma2(wr2[31], L2[31], a1);
      a2 = fma2(wr2[32], L2[32], a2);
      const v2f sum = (a0 + a1) + a2;
      ov[cc] = bl[c] + (sum.x + sum.y);
    }
    float4 o;
    o.x = ov[0]; o.y = ov[1]; o.z = ov[2]; o.w = ov[3];
    reinterpret_cast<float4*>(ob)[c4] = o;
  }
}

extern "C" void kernel_launch(void* const* d_in, const int* in_sizes, int n_in,
                              void* d_out, int out_size, void* d_ws, size_t ws_size,
                              hipStream_t stream) {
  const float* x = (const float*)d_in[0];
  const float* w1 = (const float*)d_in[1];
  const float* w2 = (const float*)d_in[2];
  const float* wlin = (const float*)d_in[3];
  const float* blin = (const float*)d_in[4];
  float* out = (float*)d_out;
  float* ws = (float*)d_ws;  // needs 3792 floats (~15 KB)
  const int B = in_sizes[0] / 144;  // 131072
  hipLaunchKernelGGL(prep_kernel, dim3(8), dim3(256), 0, stream,
                     w1, w2, wlin, blin, ws);
  const int grid = (B + 255) / 256;
  hipLaunchKernelGGL(manifold_kernel, dim3(grid), dim3(256), 0, stream,
                     x, ws, out, B);
}

// Round 7
// 270.868 us; speedup vs baseline: 1.0051x; 1.0051x over previous
//
#include <hip/hip_runtime.h>
#include <math.h>

// SPDNet collapse: both ReEig clamps are inactive (lambda_min >= 1e-3 > 1e-4 by
// construction), so:  out = vec(logm(V^T x V)) @ w_lin^T + b_lin,  V = w1@w2.
// One thread per matrix; 11x11 Jacobi fully unrolled in registers.
//
// R14 = R13 with the formation-packing bug fixed (R13 failed absmax 5.09):
//   the "covered by pk at l-1" skip fired for l==k with k odd, where the row
//   loop starts AT l=k and no pk at l-1 ever ran -> M(k,k) stayed 0 for the
//   odd arow rows k=1,5,9 (UT(k,k)=11,45,63 all odd). Three zeroed diagonals
//   -> eigvals at clamp -> log(1e-4) -> O(5) error. Fix: skip requires l>k;
//   l==k odd now takes the scalar branch (w2[r][k>>1].y).
//
// R12 rationale (still the live hypothesis this round tests):
//  (R11 post-mortem: 1-round U-pipelining regressed 193->198us; with R10 the
//  model is "dur ~ static instr count, ~9.3 cyc/instr, insensitive to
//  source-level ILP". Occupancy HW-closed: 2 waves/SIMD needs <=128 VGPR;
//  M66+U132 can't fit; U-in-LDS needs 270KB/CU > 160KB.)
//  - revert R11: exact R10 round order (cs x5 then fused apply x5).
//  - M stored as v2f M2[33] over the linear UT index; formation accumulates
//    aligned even-l pairs with ONE pk_fma using w2[r][l/2] directly. arow rows
//    (par(UT(k,k))==par(k)): 15 pk + rest scalar vs 66 scalar.
//  - L = U diag(lw) U^T: output pairs (j even, j+1) read exactly U2[k*6+j/2]
//    -> 11 pk_fma produce two entries.
//  - all shaves keep per-entry fma chain order -> absmax must stay EXACTLY
//    0.01757812 (canary).
//  - keep: waves_per_eu(1,1), NSWEEP 5, copysign cs chain, packed U/epilogue,
//    prep kernel + wave-uniform epilogue.

#define NSWEEP 5

// d_ws float layout: [0..143] V (12x12, col 11 zero) | [160..211] b_lin |
//                    [256..256+52*68) Ws_sym rows padded to 68
#define WS_V 0
#define WS_B 160
#define WS_W 256

typedef float v2f __attribute__((ext_vector_type(2)));

__device__ __forceinline__ v2f fma2(v2f a, v2f b, v2f c) {
  return __builtin_elementwise_fma(a, b, c);
}
__device__ __forceinline__ v2f sp2(float x) {
  v2f r; r.x = x; r.y = x; return r;
}

__device__ __forceinline__ constexpr int UT(int i, int j) { // i<=j, n=11 upper tri
  return i * 11 - (i * (i - 1)) / 2 + (j - i);
}

// scalar access into the packed triangle (e constant-folds in unrolled code)
__device__ __forceinline__ float mget(const v2f (&M2)[33], int e) {
  return (e & 1) ? M2[e >> 1].y : M2[e >> 1].x;
}
__device__ __forceinline__ void mset(v2f (&M2)[33], int e, float v) {
  if (e & 1) M2[e >> 1].y = v;
  else       M2[e >> 1].x = v;
}

template <int P, int Q>
__device__ __forceinline__ void csCompute(const v2f (&M2)[33], float& c, float& s,
                                          float& t) {
  const float app = mget(M2, UT(P, P)), aqq = mget(M2, UT(Q, Q)),
              apq = mget(M2, UT(P, Q));
  const float d2 = aqq - app;
  const float a2 = apq + apq;
  const float r = __builtin_amdgcn_sqrtf(
      __builtin_fmaf(d2, d2, __builtin_fmaf(a2, a2, 1e-60f)));
  const float den = d2 + __builtin_copysignf(r, d2);
  t = a2 * __builtin_amdgcn_rcpf(den);
  c = __builtin_amdgcn_rsqf(__builtin_fmaf(t, t, 1.0f));
  s = t * c;
}

// M2: packed scalar upper-tri (33 v2f). U2: column-major packed, col j =
// U2[j*6 .. j*6+5], rows (2*r2, 2*r2+1); row 11 is padding (never read back).
template <int P, int Q>
__device__ __forceinline__ void applyRot(v2f (&M2)[33], v2f (&U2)[66], float c,
                                         float s, float t) {
  const float apq = mget(M2, UT(P, Q));
#pragma unroll
  for (int k = 0; k < 11; ++k) {
    if (k == P || k == Q) continue;
    const int ikp = (k < P) ? UT(k, P) : UT(P, k);
    const int ikq = (k < Q) ? UT(k, Q) : UT(Q, k);
    const float akp = mget(M2, ikp), akq = mget(M2, ikq);
    mset(M2, ikp, __builtin_fmaf(c, akp, -s * akq));
    mset(M2, ikq, __builtin_fmaf(s, akp, c * akq));
  }
  mset(M2, UT(P, P), __builtin_fmaf(-t, apq, mget(M2, UT(P, P))));
  mset(M2, UT(Q, Q), __builtin_fmaf(t, apq, mget(M2, UT(Q, Q))));
  mset(M2, UT(P, Q), 0.0f);
  const v2f c2 = sp2(c), s2 = sp2(s);
#pragma unroll
  for (int r2 = 0; r2 < 6; ++r2) {
    const v2f up = U2[P * 6 + r2], uq = U2[Q * 6 + r2];
    U2[P * 6 + r2] = fma2(c2, up, -(s2 * uq));   // c*up - s*uq  (2 rows/op)
    U2[Q * 6 + r2] = fma2(s2, up, c2 * uq);      // s*up + c*uq
  }
}

// Round-robin pairs: round R, K=1..5 -> 5 disjoint pairs; 11 rounds = all 55.
template <int R, int K>
struct PairRR {
  static constexpr int A0 = (R + K) % 11;
  static constexpr int B0 = (R + 11 - K) % 11;
  static constexpr int P = A0 < B0 ? A0 : B0;
  static constexpr int Q = A0 < B0 ? B0 : A0;
};

template <int R>
__device__ __forceinline__ void jround(v2f (&M2)[33], v2f (&U2)[66]) {
  float c1, s1, t1, c2, s2, t2, c3, s3, t3, c4, s4, t4, c5, s5, t5;
  csCompute<PairRR<R, 1>::P, PairRR<R, 1>::Q>(M2, c1, s1, t1);
  csCompute<PairRR<R, 2>::P, PairRR<R, 2>::Q>(M2, c2, s2, t2);
  csCompute<PairRR<R, 3>::P, PairRR<R, 3>::Q>(M2, c3, s3, t3);
  csCompute<PairRR<R, 4>::P, PairRR<R, 4>::Q>(M2, c4, s4, t4);
  csCompute<PairRR<R, 5>::P, PairRR<R, 5>::Q>(M2, c5, s5, t5);
  applyRot<PairRR<R, 1>::P, PairRR<R, 1>::Q>(M2, U2, c1, s1, t1);
  applyRot<PairRR<R, 2>::P, PairRR<R, 2>::Q>(M2, U2, c2, s2, t2);
  applyRot<PairRR<R, 3>::P, PairRR<R, 3>::Q>(M2, U2, c3, s3, t3);
  applyRot<PairRR<R, 4>::P, PairRR<R, 4>::Q>(M2, U2, c4, s4, t4);
  applyRot<PairRR<R, 5>::P, PairRR<R, 5>::Q>(M2, U2, c5, s5, t5);
}

template <int R>
struct RoundSeq {
  static __device__ __forceinline__ void run(v2f (&M2)[33], v2f (&U2)[66]) {
    jround<R>(M2, U2);
    if constexpr (R < 10) RoundSeq<R + 1>::run(M2, U2);
  }
};

__global__ __launch_bounds__(256) void prep_kernel(
    const float* __restrict__ w1, const float* __restrict__ w2,
    const float* __restrict__ wlin, const float* __restrict__ blin,
    float* __restrict__ ws) {
  const int g = blockIdx.x * 256 + threadIdx.x;
  const int gs = gridDim.x * 256;
  for (int idx = g; idx < 144; idx += gs) {
    const int i = idx / 12, l = idx % 12;
    float acc = 0.f;
    if (l < 11) {
#pragma unroll
      for (int j = 0; j < 12; ++j) acc = __builtin_fmaf(w1[i * 12 + j], w2[j * 11 + l], acc);
    }
    ws[WS_V + idx] = acc;
  }
  for (int idx = g; idx < 52; idx += gs) ws[WS_B + idx] = blin[idx];
  for (int idx = g; idx < 52 * 68; idx += gs) {
    const int c = idx / 68, t = idx % 68;
    float v = 0.f;
    if (t < 66) {
      int i = 0, rem = t;
      while (rem >= 11 - i) { rem -= 11 - i; ++i; }
      const int j = i + rem;
      v = wlin[c * 121 + i * 11 + j];
      if (i != j) v += wlin[c * 121 + j * 11 + i];
    }
    ws[WS_W + idx] = v;
  }
}

__global__ __attribute__((amdgpu_flat_work_group_size(256, 256)))
__attribute__((amdgpu_waves_per_eu(1, 1)))
void manifold_kernel(const float* __restrict__ x, const float* __restrict__ ws,
                     float* __restrict__ out, int B) {
  __shared__ __align__(16) float sV[12 * 12];
  const int tid = threadIdx.x;
  if (tid < 36) {
    reinterpret_cast<float4*>(sV)[tid] =
        reinterpret_cast<const float4*>(ws + WS_V)[tid];
  }
  __syncthreads();

  const int b = blockIdx.x * 256 + tid;
  if (b >= B) return;

  // ---- Formation: M = V^T (X V), 4 X-rows per block. w packed along l
  // (v2f w2[4][6]; pad lane l=11 multiplies V col 11 == 0, stays 0).
  // M packed over the linear UT index (v2f M2[33]); arow rows accumulate
  // even-l pairs with one pk_fma on w2[r][l/2]. Skip only when the covering
  // pk actually ran (l > k).
  v2f M2[33];
#pragma unroll
  for (int e = 0; e < 33; ++e) { M2[e].x = 0.f; M2[e].y = 0.f; }
  const float4* xb4 = reinterpret_cast<const float4*>(x + (size_t)b * 144);
#pragma unroll 1
  for (int ib = 0; ib < 3; ++ib) {
    float xr[4][12];
#pragma unroll
    for (int r = 0; r < 4; ++r) {
      const float4 a0 = xb4[(ib * 4 + r) * 3 + 0];
      const float4 a1 = xb4[(ib * 4 + r) * 3 + 1];
      const float4 a2 = xb4[(ib * 4 + r) * 3 + 2];
      xr[r][0] = a0.x; xr[r][1] = a0.y; xr[r][2] = a0.z; xr[r][3] = a0.w;
      xr[r][4] = a1.x; xr[r][5] = a1.y; xr[r][6] = a1.z; xr[r][7] = a1.w;
      xr[r][8] = a2.x; xr[r][9] = a2.y; xr[r][10] = a2.z; xr[r][11] = a2.w;
    }
    v2f w2[4][6];
#pragma unroll
    for (int r = 0; r < 4; ++r)
#pragma unroll
      for (int l2 = 0; l2 < 6; ++l2) { w2[r][l2].x = 0.f; w2[r][l2].y = 0.f; }
#pragma unroll
    for (int j = 0; j < 12; ++j) {
      v2f vj[6];
      {
        const float4 v0 = *reinterpret_cast<const float4*>(&sV[j * 12 + 0]);
        const float4 v1 = *reinterpret_cast<const float4*>(&sV[j * 12 + 4]);
        const float4 v2 = *reinterpret_cast<const float4*>(&sV[j * 12 + 8]);
        vj[0].x = v0.x; vj[0].y = v0.y; vj[1].x = v0.z; vj[1].y = v0.w;
        vj[2].x = v1.x; vj[2].y = v1.y; vj[3].x = v1.z; vj[3].y = v1.w;
        vj[4].x = v2.x; vj[4].y = v2.y; vj[5].x = v2.z; vj[5].y = v2.w;
      }
#pragma unroll
      for (int r = 0; r < 4; ++r) {
        const v2f xb = sp2(xr[r][j]);
#pragma unroll
        for (int l2 = 0; l2 < 6; ++l2) w2[r][l2] = fma2(xb, vj[l2], w2[r][l2]);
      }
    }
#pragma unroll
    for (int r = 0; r < 4; ++r) {
      const int i = ib * 4 + r;
      const float4 u0 = *reinterpret_cast<const float4*>(&sV[i * 12 + 0]);
      const float4 u1 = *reinterpret_cast<const float4*>(&sV[i * 12 + 4]);
      const float4 u2 = *reinterpret_cast<const float4*>(&sV[i * 12 + 8]);
      const float ui[11] = {u0.x, u0.y, u0.z, u0.w, u1.x, u1.y, u1.z, u1.w,
                            u2.x, u2.y, u2.z};
#pragma unroll
      for (int k = 0; k < 11; ++k) {
        const bool arow = ((UT(k, k) & 1) == (k & 1));  // l-parity == e-parity
#pragma unroll
        for (int l = k; l < 11; ++l) {
          const int e = UT(k, l);
          if (arow && ((l & 1) == 0) && (l < 10)) {
            // one pk_fma covers (k,l) and (k,l+1); e is even here
            M2[e >> 1] = fma2(sp2(ui[k]), w2[r][l >> 1], M2[e >> 1]);
          } else if (arow && ((l & 1) == 1) && (l > k)) {
            // covered by the pk at l-1 (l-1 >= k, even, <10: it ran)
          } else {
            // scalar: l==10, non-arow rows, and the l==k odd diagonal
            const float wvl = (l & 1) ? w2[r][l >> 1].y : w2[r][l >> 1].x;
            mset(M2, e, __builtin_fmaf(ui[k], wvl, mget(M2, e)));
          }
        }
      }
    }
  }

  // ---- Jacobi eigendecomposition; U column-major packed in v2f ----
  v2f U2[66];
#pragma unroll
  for (int e = 0; e < 66; ++e) { U2[e].x = 0.f; U2[e].y = 0.f; }
#pragma unroll
  for (int d = 0; d < 11; ++d) {
    if (d & 1) U2[d * 6 + (d >> 1)].y = 1.f;
    else       U2[d * 6 + (d >> 1)].x = 1.f;
  }
#pragma unroll 1
  for (int sweep = 0; sweep < NSWEEP; ++sweep) {
    RoundSeq<0>::run(M2, U2);
  }

  // ---- eigen-log (clamp matches the reference's preceding ReEig) ----
  float lw[11];
#pragma unroll
  for (int k = 0; k < 11; ++k) lw[k] = __logf(fmaxf(mget(M2, UT(k, k)), 1e-4f));

  // ---- L = U diag(lw) U^T into packed v2f L2[33].
  // Output pairs (j even, j+1): both rows live in U2[k*6 + j/2] -> 11 pk_fma
  // produce two entries. Per-entry k-order identical to scalar -> bit-identical.
  v2f L2[33];
#pragma unroll
  for (int i = 0; i < 11; ++i) {
    float tk[11];
#pragma unroll
    for (int k = 0; k < 11; ++k) {
      const v2f u = U2[k * 6 + (i >> 1)];
      const float uik = (i & 1) ? u.y : u.x;
      tk[k] = lw[k] * uik;
    }
#pragma unroll
    for (int j = i; j < 11; ++j) {
      if (((j & 1) == 0) && (j < 10)) {
        v2f acc2 = sp2(0.f);
#pragma unroll
        for (int k = 0; k < 11; ++k)
          acc2 = fma2(sp2(tk[k]), U2[k * 6 + (j >> 1)], acc2);
        const int e = UT(i, j);
        if (e & 1) { L2[e >> 1].y = acc2.x; L2[(e >> 1) + 1].x = acc2.y; }
        else       { L2[e >> 1].x = acc2.x; L2[e >> 1].y = acc2.y; }
      } else if (((j & 1) == 1) && (j > i)) {
        // covered by the pair at j-1
      } else {
        float acc = 0.f;
#pragma unroll
        for (int k = 0; k < 11; ++k) {
          const v2f u = U2[k * 6 + (j >> 1)];
          const float ujk = (j & 1) ? u.y : u.x;
          acc = __builtin_fmaf(tk[k], ujk, acc);
        }
        const int e = UT(i, j);
        if (e & 1) L2[e >> 1].y = acc;
        else       L2[e >> 1].x = acc;
      }
    }
  }

  // ---- epilogue: packed pk_fma; weights wave-uniform (SGPR-pair source) ----
  const float* __restrict__ wsym = ws + WS_W;
  const float* __restrict__ bl = ws + WS_B;
  float* ob = out + (size_t)b * 52;
#pragma unroll 1
  for (int c4 = 0; c4 < 13; ++c4) {
    float ov[4];
#pragma unroll
    for (int cc = 0; cc < 4; ++cc) {
      const int c = c4 * 4 + cc;
      const v2f* __restrict__ wr2 = reinterpret_cast<const v2f*>(wsym + c * 68);
      v2f a0 = sp2(0.f), a1 = sp2(0.f), a2 = sp2(0.f);
#pragma unroll
      for (int t = 0; t < 30; t += 3) {
        a0 = fma2(wr2[t + 0], L2[t + 0], a0);
        a1 = fma2(wr2[t + 1], L2[t + 1], a1);
        a2 = fma2(wr2[t + 2], L2[t + 2], a2);
      }
      a0 = fma2(wr2[30], L2[30], a0);
      a1 = fma2(wr2[31], L2[31], a1);
      a2 = fma2(wr2[32], L2[32], a2);
      const v2f sum = (a0 + a1) + a2;
      ov[cc] = bl[c] + (sum.x + sum.y);
    }
    float4 o;
    o.x = ov[0]; o.y = ov[1]; o.z = ov[2]; o.w = ov[3];
    reinterpret_cast<float4*>(ob)[c4] = o;
  }
}

extern "C" void kernel_launch(void* const* d_in, const int* in_sizes, int n_in,
                              void* d_out, int out_size, void* d_ws, size_t ws_size,
                              hipStream_t stream) {
  const float* x = (const float*)d_in[0];
  const float* w1 = (const float*)d_in[1];
  const float* w2 = (const float*)d_in[2];
  const float* wlin = (const float*)d_in[3];
  const float* blin = (const float*)d_in[4];
  float* out = (float*)d_out;
  float* ws = (float*)d_ws;  // needs 3792 floats (~15 KB)
  const int B = in_sizes[0] / 144;  // 131072
  hipLaunchKernelGGL(prep_kernel, dim3(8), dim3(256), 0, stream,
                     w1, w2, wlin, blin, ws);
  const int grid = (B + 255) / 256;
  hipLaunchKernelGGL(manifold_kernel, dim3(grid), dim3(256), 0, stream,
                     x, ws, out, B);
}